// Round 1
// 564.626 us; speedup vs baseline: 1.0008x; 1.0008x over previous
//
#include <hip/hip_runtime.h>

// Wave equation velocity-Verlet, 23x23 periodic grid, 2 components (x, v).
// One block per batch element; grid state double-buffered in LDS.
// Reuses a2(step n) as a1(step n+1) -> one Laplacian per step.
//
// Key change this round: per-step barrier no longer drains vmcnt.
// __syncthreads() emits "s_waitcnt vmcnt(0) lgkmcnt(0); s_barrier", which
// forces each step's 4.2 KB global trajectory store to fully reach HBM
// before any wave proceeds (~400-700 cy serialized per step). The barrier
// only needs to order the LDS double-buffer traffic, so we wait lgkmcnt
// only and let stores stream across steps at HBM bandwidth.

#define S 23
#define CELLS (S * S)   // 529
#define NT 576          // 9 waves; threads >= CELLS, one cell per thread

// LDS-only workgroup barrier: orders ds_write/ds_read across waves without
// draining outstanding global stores (vmcnt). The "memory" clobbers keep
// the compiler from moving LDS ops across the barrier.
__device__ __forceinline__ void lds_barrier() {
    asm volatile("s_waitcnt lgkmcnt(0)" ::: "memory");
    __builtin_amdgcn_s_barrier();
    asm volatile("" ::: "memory");
}

__global__ __launch_bounds__(NT, 1)
void wave_step_kernel(const float* __restrict__ y0,
                      const float* __restrict__ dt_p,
                      const int* __restrict__ nsteps_p,
                      const int* __restrict__ inc_p,
                      float* __restrict__ out)
{
    const int b = blockIdx.x;
    const int c = threadIdx.x;

    const float dt = *dt_p;
    const int nsteps = *nsteps_p;
    const int inc = *inc_p;

    const float c2 = 9.0f;              // WAVE_SPEED^2
    const float half_dt = 0.5f * dt;
    const float half_dt2 = 0.5f * dt * dt;

    // Double-buffered position field in LDS (4.2 KB total).
    __shared__ float xs[2][CELLS];

    const int T = nsteps + (inc ? 1 : 0);
    const float2* y0v = (const float2*)y0 + (size_t)b * CELLS;
    float2* outv = (float2*)out + (size_t)b * T * CELLS;

    float x = 0.0f, v = 0.0f, a = 0.0f;
    int iL = 0, iR = 0, iU = 0, iD = 0;
    const bool active = (c < CELLS);

    if (active) {
        float2 xv = y0v[c];             // interleaved (position, velocity)
        x = xv.x;
        v = xv.y;
        int i = c / S;
        int j = c - i * S;
        iL = i * S + (j == 0 ? S - 1 : j - 1);
        iR = i * S + (j == S - 1 ? 0 : j + 1);
        iU = (i == 0 ? S - 1 : i - 1) * S + j;
        iD = (i == S - 1 ? 0 : i + 1) * S + j;
        xs[0][c] = x;
        if (inc) outv[c] = xv;          // t=0 row is y0 itself
    }
    lds_barrier();

    if (active) {
        a = c2 * (xs[0][iL] + xs[0][iR] + xs[0][iU] + xs[0][iD] - 4.0f * x);
    }

    float2* outt = outv + (inc ? CELLS : 0);
    int buf = 0;

    for (int t = 0; t < nsteps; ++t) {
        float xn = 0.0f;
        if (active) {
            xn = x + v * dt + a * half_dt2;
            xs[buf ^ 1][c] = xn;
        }
        lds_barrier();                  // LDS-only: global stores keep streaming
        if (active) {
            const float* xb = xs[buf ^ 1];
            float an = c2 * (xb[iL] + xb[iR] + xb[iU] + xb[iD] - 4.0f * xn);
            float vn = v + (a + an) * half_dt;
            float2 o;
            o.x = xn;
            o.y = vn;
            outt[(size_t)t * CELLS + c] = o;   // coalesced 8B/lane store
            x = xn;
            v = vn;
            a = an;
        }
        buf ^= 1;
    }
}

extern "C" void kernel_launch(void* const* d_in, const int* in_sizes, int n_in,
                              void* d_out, int out_size, void* d_ws, size_t ws_size,
                              hipStream_t stream) {
    const float* y0 = (const float*)d_in[0];
    const float* dt_p = (const float*)d_in[1];
    const int* nsteps_p = (const int*)d_in[2];
    const int* inc_p = (const int*)d_in[3];
    float* out = (float*)d_out;

    const int B = in_sizes[0] / (CELLS * 2);   // 256

    wave_step_kernel<<<B, NT, 0, stream>>>(y0, dt_p, nsteps_p, inc_p, out);
}